// Round 1
// baseline (4196.699 us; speedup 1.0000x reference)
//
#include <hip/hip_runtime.h>

#define N_NODES 50000
#define N_EDGES 800000

__global__ void k_init_deg(float* deg) {
    int i = blockIdx.x * 256 + threadIdx.x;
    if (i < N_NODES) deg[i] = 1.0f;  // self-loop pre-counted
}

__global__ void k_count(const int* __restrict__ dst, float* __restrict__ deg) {
    int e = blockIdx.x * 256 + threadIdx.x;
    if (e < N_EDGES) atomicAdd(&deg[dst[e]], 1.0f);
}

__global__ void k_dinv(float* deg) {
    int i = blockIdx.x * 256 + threadIdx.x;
    if (i < N_NODES) deg[i] = rsqrtf(deg[i]);  // deg >= 1 always
}

// out[row0..row0+15][0..NC) = A[rows][K] @ W[K][NC]
// blockDim = NC threads. Thread = (col-group jc of 4, row-group rc of 4).
template<int K, int NC>
__global__ void k_gemm(const float* __restrict__ A, const float* __restrict__ W,
                       float* __restrict__ out) {
    constexpr int RPB = 16;
    constexpr int LSTR = RPB + 4;  // pad: keeps float4 alignment, spreads banks
    __shared__ float lds[K * LSTR];
    const int row0 = blockIdx.x * RPB;
    const int t = threadIdx.x;

    // Stage A tile transposed: lds[k][r]
    constexpr int TOT = K * RPB;
    #pragma unroll
    for (int i = 0; i < TOT / NC; ++i) {
        int idx = i * NC + t;
        int r = idx / K, k = idx % K;
        lds[k * LSTR + r] = A[(size_t)(row0 + r) * K + k];
    }
    __syncthreads();

    const int jc = (t % (NC / 4)) * 4;
    const int rc = (t / (NC / 4)) * 4;
    float4 acc0 = {0,0,0,0}, acc1 = {0,0,0,0}, acc2 = {0,0,0,0}, acc3 = {0,0,0,0};
    #pragma unroll 8
    for (int k = 0; k < K; ++k) {
        float4 w = *(const float4*)&W[k * NC + jc];
        float4 a = *(const float4*)&lds[k * LSTR + rc];  // wave-uniform -> broadcast
        acc0.x = fmaf(a.x, w.x, acc0.x); acc0.y = fmaf(a.x, w.y, acc0.y);
        acc0.z = fmaf(a.x, w.z, acc0.z); acc0.w = fmaf(a.x, w.w, acc0.w);
        acc1.x = fmaf(a.y, w.x, acc1.x); acc1.y = fmaf(a.y, w.y, acc1.y);
        acc1.z = fmaf(a.y, w.z, acc1.z); acc1.w = fmaf(a.y, w.w, acc1.w);
        acc2.x = fmaf(a.z, w.x, acc2.x); acc2.y = fmaf(a.z, w.y, acc2.y);
        acc2.z = fmaf(a.z, w.z, acc2.z); acc2.w = fmaf(a.z, w.w, acc2.w);
        acc3.x = fmaf(a.w, w.x, acc3.x); acc3.y = fmaf(a.w, w.y, acc3.y);
        acc3.z = fmaf(a.w, w.z, acc3.z); acc3.w = fmaf(a.w, w.w, acc3.w);
    }
    *(float4*)&out[(size_t)(row0 + rc + 0) * NC + jc] = acc0;
    *(float4*)&out[(size_t)(row0 + rc + 1) * NC + jc] = acc1;
    *(float4*)&out[(size_t)(row0 + rc + 2) * NC + jc] = acc2;
    *(float4*)&out[(size_t)(row0 + rc + 3) * NC + jc] = acc3;
}

// out[i][:] = dinv[i]^2 * x[i][:] + bias[:]   (self-loop term + bias; plain store)
template<int F>
__global__ void k_agg_init(const float* __restrict__ x, const float* __restrict__ dinv,
                           const float* __restrict__ bias, float* __restrict__ out) {
    constexpr int F4 = F / 4;
    int t = blockIdx.x * 256 + threadIdx.x;     // over N*F/4 float4s
    int i = t / F4;
    int j = t % F4;
    if (i >= N_NODES) return;
    float di = dinv[i];
    float c = di * di;
    float4 v = ((const float4*)x)[t];
    float4 b = ((const float4*)bias)[j];
    float4 o;
    o.x = fmaf(c, v.x, b.x); o.y = fmaf(c, v.y, b.y);
    o.z = fmaf(c, v.z, b.z); o.w = fmaf(c, v.w, b.w);
    ((float4*)out)[t] = o;
}

// out[dst[e]][:] += dinv[src]*dinv[dst] * x[src[e]][:]   (F/4 lanes per edge)
template<int F>
__global__ void k_agg_edges(const float* __restrict__ x, const int* __restrict__ src,
                            const int* __restrict__ dst, const float* __restrict__ dinv,
                            float* __restrict__ out) {
    constexpr int L = F / 4;
    int t = blockIdx.x * 256 + threadIdx.x;
    int e = t / L;
    int lane = t % L;
    if (e >= N_EDGES) return;
    int s = src[e], d = dst[e];
    float coef = dinv[s] * dinv[d];
    float4 v = ((const float4*)(x + (size_t)s * F))[lane];
    float* o = out + (size_t)d * F + lane * 4;
    atomicAdd(o + 0, coef * v.x);
    atomicAdd(o + 1, coef * v.y);
    atomicAdd(o + 2, coef * v.z);
    atomicAdd(o + 3, coef * v.w);
}

extern "C" void kernel_launch(void* const* d_in, const int* in_sizes, int n_in,
                              void* d_out, int out_size, void* d_ws, size_t ws_size,
                              hipStream_t stream) {
    const float* emb = (const float*)d_in[0];   // [50000][128]
    const float* W1  = (const float*)d_in[1];   // [128][256]
    const float* b1  = (const float*)d_in[2];   // [256]
    const float* W2  = (const float*)d_in[3];   // [256][128]
    const float* b2  = (const float*)d_in[4];   // [128]
    const int*   ei  = (const int*)d_in[5];     // [2][800000]
    const int* src = ei;
    const int* dst = ei + N_EDGES;

    char* ws = (char*)d_ws;
    float* dinv = (float*)ws;                         // 200 KB
    float* x1   = (float*)(ws + (4ull  << 20));       // 51.2 MB
    float* h    = (float*)(ws + (56ull << 20));       // 51.2 MB
    float* x2   = x1;                                 // reuse (x1 dead after agg1)
    float* out  = (float*)d_out;                      // [50000][128]

    // degree + normalization
    k_init_deg<<<196, 256, 0, stream>>>(dinv);
    k_count<<<(N_EDGES + 255) / 256, 256, 0, stream>>>(dst, dinv);
    k_dinv<<<196, 256, 0, stream>>>(dinv);

    // layer 1: x1 = emb @ W1 ; h = D^-1/2 (A+I) D^-1/2 x1 + b1
    k_gemm<128, 256><<<N_NODES / 16, 256, 0, stream>>>(emb, W1, x1);
    k_agg_init<256><<<N_NODES * (256 / 4) / 256, 256, 0, stream>>>(x1, dinv, b1, h);
    k_agg_edges<256><<<N_EDGES * 64 / 256, 256, 0, stream>>>(x1, src, dst, dinv, h);

    // layer 2: x2 = h @ W2 ; out = D^-1/2 (A+I) D^-1/2 x2 + b2
    k_gemm<256, 128><<<N_NODES / 16, 128, 0, stream>>>(h, W2, x2);
    k_agg_init<128><<<N_NODES * (128 / 4) / 256, 256, 0, stream>>>(x2, dinv, b2, out);
    k_agg_edges<128><<<N_EDGES * 32 / 256, 256, 0, stream>>>(x2, src, dst, dinv, out);
}

// Round 2
// 503.421 us; speedup vs baseline: 8.3364x; 8.3364x over previous
//
#include <hip/hip_runtime.h>

#define N_NODES 50000
#define N_EDGES 800000

// ---------- degree / CSR build ----------

__global__ void k_zero(int* counts) {
    int i = blockIdx.x * 256 + threadIdx.x;
    if (i < N_NODES) counts[i] = 0;
}

__global__ void k_hist(const int* __restrict__ dst, int* __restrict__ counts) {
    int e = blockIdx.x * 256 + threadIdx.x;
    if (e < N_EDGES) atomicAdd(&counts[dst[e]], 1);
}

__global__ void k_dinv(const int* __restrict__ counts, float* __restrict__ dinv) {
    int i = blockIdx.x * 256 + threadIdx.x;
    if (i < N_NODES) dinv[i] = rsqrtf((float)(counts[i] + 1));  // +1 self-loop
}

// Single-block exclusive scan of counts[50000] -> row_ptr, fill. 1024 threads.
__global__ void k_scan(const int* __restrict__ counts, int* __restrict__ row_ptr,
                       int* __restrict__ fill) {
    __shared__ int partial[1024];
    const int t = threadIdx.x;
    const int CH = (N_NODES + 1023) / 1024;  // 49 per thread
    const int base = t * CH;
    int sum = 0;
    for (int i = 0; i < CH; ++i) {
        int idx = base + i;
        if (idx < N_NODES) sum += counts[idx];
    }
    partial[t] = sum;
    __syncthreads();
    int val = sum;
    for (int off = 1; off < 1024; off <<= 1) {  // Hillis-Steele inclusive
        int other = (t >= off) ? partial[t - off] : 0;
        __syncthreads();
        val += other;
        partial[t] = val;
        __syncthreads();
    }
    int run = val - sum;  // exclusive offset of this chunk
    for (int i = 0; i < CH; ++i) {
        int idx = base + i;
        if (idx < N_NODES) {
            row_ptr[idx] = run;
            fill[idx] = run;
            run += counts[idx];
        }
    }
    if (t == 0) row_ptr[N_NODES] = N_EDGES;
}

__global__ void k_fill(const int* __restrict__ src, const int* __restrict__ dst,
                       int* __restrict__ fill, int* __restrict__ csr_src) {
    int e = blockIdx.x * 256 + threadIdx.x;
    if (e >= N_EDGES) return;
    int pos = atomicAdd(&fill[dst[e]], 1);
    csr_src[pos] = src[e];
}

// ---------- gather aggregation (F=128, one wave per dst node) ----------
// out[d] = dinv[d] * sum_{s in N(d)} dinv[s]*x[s]  +  dinv[d]^2 * x[d]  (+ bias)
__global__ void k_gather128(const float* __restrict__ x, const int* __restrict__ csr,
                            const int* __restrict__ rp, const float* __restrict__ dinv,
                            const float* __restrict__ bias, float* __restrict__ out) {
    int node = blockIdx.x * 4 + (threadIdx.x >> 6);
    int lane = threadIdx.x & 63;
    int beg = rp[node], end = rp[node + 1];
    float dd = dinv[node];
    float2 acc = make_float2(0.f, 0.f);
    for (int j = beg; j < end; ++j) {
        int s = csr[j];                       // wave-uniform
        float c = dinv[s];
        float2 v = ((const float2*)(x + (size_t)s * 128))[lane];
        acc.x = fmaf(c, v.x, acc.x);
        acc.y = fmaf(c, v.y, acc.y);
    }
    float2 self = ((const float2*)(x + (size_t)node * 128))[lane];
    float dd2 = dd * dd;
    float2 o;
    o.x = fmaf(dd, acc.x, dd2 * self.x);
    o.y = fmaf(dd, acc.y, dd2 * self.y);
    if (bias) {
        float2 b = ((const float2*)bias)[lane];
        o.x += b.x; o.y += b.y;
    }
    ((float2*)(out + (size_t)node * 128))[lane] = o;
}

// ---------- GEMM: out[16 rows][NC] = A[16][K] @ W[K][NC] (+ bias) ----------
template<int K, int NC>
__global__ void k_gemm(const float* __restrict__ A, const float* __restrict__ W,
                       const float* __restrict__ bias, float* __restrict__ out) {
    constexpr int RPB = 16;
    constexpr int LSTR = RPB + 4;
    __shared__ float lds[K * LSTR];
    const int row0 = blockIdx.x * RPB;
    const int t = threadIdx.x;

    constexpr int TOT = K * RPB;
    #pragma unroll
    for (int i = 0; i < TOT / NC; ++i) {
        int idx = i * NC + t;
        int r = idx / K, k = idx % K;
        lds[k * LSTR + r] = A[(size_t)(row0 + r) * K + k];
    }
    __syncthreads();

    const int jc = (t % (NC / 4)) * 4;
    const int rc = (t / (NC / 4)) * 4;
    float4 acc0 = {0,0,0,0}, acc1 = {0,0,0,0}, acc2 = {0,0,0,0}, acc3 = {0,0,0,0};
    #pragma unroll 8
    for (int k = 0; k < K; ++k) {
        float4 w = *(const float4*)&W[k * NC + jc];
        float4 a = *(const float4*)&lds[k * LSTR + rc];
        acc0.x = fmaf(a.x, w.x, acc0.x); acc0.y = fmaf(a.x, w.y, acc0.y);
        acc0.z = fmaf(a.x, w.z, acc0.z); acc0.w = fmaf(a.x, w.w, acc0.w);
        acc1.x = fmaf(a.y, w.x, acc1.x); acc1.y = fmaf(a.y, w.y, acc1.y);
        acc1.z = fmaf(a.y, w.z, acc1.z); acc1.w = fmaf(a.y, w.w, acc1.w);
        acc2.x = fmaf(a.z, w.x, acc2.x); acc2.y = fmaf(a.z, w.y, acc2.y);
        acc2.z = fmaf(a.z, w.z, acc2.z); acc2.w = fmaf(a.z, w.w, acc2.w);
        acc3.x = fmaf(a.w, w.x, acc3.x); acc3.y = fmaf(a.w, w.y, acc3.y);
        acc3.z = fmaf(a.w, w.z, acc3.z); acc3.w = fmaf(a.w, w.w, acc3.w);
    }
    if (bias) {
        float4 b = *(const float4*)&bias[jc];
        acc0.x += b.x; acc0.y += b.y; acc0.z += b.z; acc0.w += b.w;
        acc1.x += b.x; acc1.y += b.y; acc1.z += b.z; acc1.w += b.w;
        acc2.x += b.x; acc2.y += b.y; acc2.z += b.z; acc2.w += b.w;
        acc3.x += b.x; acc3.y += b.y; acc3.z += b.z; acc3.w += b.w;
    }
    *(float4*)&out[(size_t)(row0 + rc + 0) * NC + jc] = acc0;
    *(float4*)&out[(size_t)(row0 + rc + 1) * NC + jc] = acc1;
    *(float4*)&out[(size_t)(row0 + rc + 2) * NC + jc] = acc2;
    *(float4*)&out[(size_t)(row0 + rc + 3) * NC + jc] = acc3;
}

extern "C" void kernel_launch(void* const* d_in, const int* in_sizes, int n_in,
                              void* d_out, int out_size, void* d_ws, size_t ws_size,
                              hipStream_t stream) {
    const float* emb = (const float*)d_in[0];   // [50000][128]
    const float* W1  = (const float*)d_in[1];   // [128][256]
    const float* b1  = (const float*)d_in[2];   // [256]
    const float* W2  = (const float*)d_in[3];   // [256][128]
    const float* b2  = (const float*)d_in[4];   // [128]
    const int*   ei  = (const int*)d_in[5];     // [2][800000]
    const int* src = ei;
    const int* dst = ei + N_EDGES;

    char* ws = (char*)d_ws;
    float* dinv    = (float*)(ws);                    // 200 KB
    int*   counts  = (int*)  (ws + (256ull << 10));   // 200 KB
    int*   row_ptr = (int*)  (ws + (512ull << 10));   // 200 KB + 4
    int*   fill    = (int*)  (ws + (768ull << 10));   // 200 KB
    int*   csr_src = (int*)  (ws + (1ull   << 20));   // 3.2 MB
    float* agg0    = (float*)(ws + (8ull   << 20));   // 25.6 MB
    float* h       = (float*)(ws + (40ull  << 20));   // 51.2 MB
    float* x2      = agg0;                            // reuse: agg0 dead after GEMM1
    float* out     = (float*)d_out;

    // CSR build + normalization
    k_zero<<<196, 256, 0, stream>>>(counts);
    k_hist<<<(N_EDGES + 255) / 256, 256, 0, stream>>>(dst, counts);
    k_dinv<<<196, 256, 0, stream>>>(counts, dinv);
    k_scan<<<1, 1024, 0, stream>>>(counts, row_ptr, fill);
    k_fill<<<(N_EDGES + 255) / 256, 256, 0, stream>>>(src, dst, fill, csr_src);

    // layer 1 (reordered): agg0 = Agg(emb); h = agg0 @ W1 + b1
    k_gather128<<<12500, 256, 0, stream>>>(emb, csr_src, row_ptr, dinv, nullptr, agg0);
    k_gemm<128, 256><<<N_NODES / 16, 256, 0, stream>>>(agg0, W1, b1, h);

    // layer 2: x2 = h @ W2 ; out = Agg(x2) + b2
    k_gemm<256, 128><<<N_NODES / 16, 128, 0, stream>>>(h, W2, nullptr, x2);
    k_gather128<<<12500, 256, 0, stream>>>(x2, csr_src, row_ptr, dinv, b2, out);
}

// Round 3
// 399.726 us; speedup vs baseline: 10.4989x; 1.2594x over previous
//
#include <hip/hip_runtime.h>

#define N_NODES 50000
#define N_EDGES 800000
#define NB 196  // ceil(N_NODES / 256)

// ---------- degree / CSR build ----------

__global__ void k_zero(int* counts) {
    int i = blockIdx.x * 256 + threadIdx.x;
    if (i < N_NODES) counts[i] = 0;
}

__global__ void k_hist(const int* __restrict__ dst, int* __restrict__ counts) {
    int e = blockIdx.x * 256 + threadIdx.x;
    if (e < N_EDGES) atomicAdd(&counts[dst[e]], 1);
}

// Stage 1: per-block sums of counts (196 blocks x 256 threads)
__global__ void k_blocksum(const int* __restrict__ counts, int* __restrict__ bsum) {
    __shared__ int lds[256];
    int t = threadIdx.x;
    int i = blockIdx.x * 256 + t;
    int v = (i < N_NODES) ? counts[i] : 0;
    lds[t] = v;
    __syncthreads();
    for (int off = 128; off > 0; off >>= 1) {
        if (t < off) lds[t] += lds[t + off];
        __syncthreads();
    }
    if (t == 0) bsum[blockIdx.x] = lds[0];
}

// Stage 2: exclusive scan of the 196 block sums (1 block)
__global__ void k_scanb(const int* __restrict__ bsum, int* __restrict__ boff) {
    __shared__ int lds[256];
    int t = threadIdx.x;
    int v = (t < NB) ? bsum[t] : 0;
    lds[t] = v;
    __syncthreads();
    for (int off = 1; off < 256; off <<= 1) {
        int o = (t >= off) ? lds[t - off] : 0;
        __syncthreads();
        lds[t] += o;
        __syncthreads();
    }
    if (t < NB) boff[t] = lds[t] - v;  // exclusive
}

// Stage 3: in-block scan + global offset -> row_ptr/fill; also dinv.
__global__ void k_scatter_rp(const int* __restrict__ counts, const int* __restrict__ boff,
                             int* __restrict__ row_ptr, int* __restrict__ fill,
                             float* __restrict__ dinv) {
    __shared__ int lds[256];
    int t = threadIdx.x;
    int i = blockIdx.x * 256 + t;
    int v = (i < N_NODES) ? counts[i] : 0;
    lds[t] = v;
    __syncthreads();
    for (int off = 1; off < 256; off <<= 1) {
        int o = (t >= off) ? lds[t - off] : 0;
        __syncthreads();
        lds[t] += o;
        __syncthreads();
    }
    if (i < N_NODES) {
        int excl = boff[blockIdx.x] + lds[t] - v;
        row_ptr[i] = excl;
        fill[i] = excl;
        dinv[i] = rsqrtf((float)(v + 1));  // +1 self-loop
    }
    if (i == 0) row_ptr[N_NODES] = N_EDGES;
}

__global__ void k_fill(const int* __restrict__ src, const int* __restrict__ dst,
                       int* __restrict__ fill, int* __restrict__ csr_src) {
    int e = blockIdx.x * 256 + threadIdx.x;
    if (e >= N_EDGES) return;
    int pos = atomicAdd(&fill[dst[e]], 1);
    csr_src[pos] = src[e];
}

// ---------- gather aggregation (F=128, one wave per dst node) ----------
// out[d] = dinv[d] * sum_{s in N(d)} dinv[s]*x[s]  +  dinv[d]^2 * x[d]  (+ bias)
__global__ void k_gather128(const float* __restrict__ x, const int* __restrict__ csr,
                            const int* __restrict__ rp, const float* __restrict__ dinv,
                            const float* __restrict__ bias, float* __restrict__ out) {
    int node = blockIdx.x * 4 + (threadIdx.x >> 6);
    int lane = threadIdx.x & 63;
    int beg = rp[node], end = rp[node + 1];
    float dd = dinv[node];
    float2 acc = make_float2(0.f, 0.f);
    for (int j = beg; j < end; ++j) {
        int s = csr[j];                       // wave-uniform
        float c = dinv[s];
        float2 v = ((const float2*)(x + (size_t)s * 128))[lane];
        acc.x = fmaf(c, v.x, acc.x);
        acc.y = fmaf(c, v.y, acc.y);
    }
    float2 self = ((const float2*)(x + (size_t)node * 128))[lane];
    float dd2 = dd * dd;
    float2 o;
    o.x = fmaf(dd, acc.x, dd2 * self.x);
    o.y = fmaf(dd, acc.y, dd2 * self.y);
    if (bias) {
        float2 b = ((const float2*)bias)[lane];
        o.x += b.x; o.y += b.y;
    }
    ((float2*)(out + (size_t)node * 128))[lane] = o;
}

// ---------- GEMM: out[16 rows][NC] = A[16][K] @ W[K][NC] (+ bias) ----------
template<int K, int NC>
__global__ void k_gemm(const float* __restrict__ A, const float* __restrict__ W,
                       const float* __restrict__ bias, float* __restrict__ out) {
    constexpr int RPB = 16;
    constexpr int LSTR = RPB + 4;
    __shared__ float lds[K * LSTR];
    const int row0 = blockIdx.x * RPB;
    const int t = threadIdx.x;

    constexpr int TOT = K * RPB;
    #pragma unroll
    for (int i = 0; i < TOT / NC; ++i) {
        int idx = i * NC + t;
        int r = idx / K, k = idx % K;
        lds[k * LSTR + r] = A[(size_t)(row0 + r) * K + k];
    }
    __syncthreads();

    const int jc = (t % (NC / 4)) * 4;
    const int rc = (t / (NC / 4)) * 4;
    float4 acc0 = {0,0,0,0}, acc1 = {0,0,0,0}, acc2 = {0,0,0,0}, acc3 = {0,0,0,0};
    #pragma unroll 8
    for (int k = 0; k < K; ++k) {
        float4 w = *(const float4*)&W[k * NC + jc];
        float4 a = *(const float4*)&lds[k * LSTR + rc];
        acc0.x = fmaf(a.x, w.x, acc0.x); acc0.y = fmaf(a.x, w.y, acc0.y);
        acc0.z = fmaf(a.x, w.z, acc0.z); acc0.w = fmaf(a.x, w.w, acc0.w);
        acc1.x = fmaf(a.y, w.x, acc1.x); acc1.y = fmaf(a.y, w.y, acc1.y);
        acc1.z = fmaf(a.y, w.z, acc1.z); acc1.w = fmaf(a.y, w.w, acc1.w);
        acc2.x = fmaf(a.z, w.x, acc2.x); acc2.y = fmaf(a.z, w.y, acc2.y);
        acc2.z = fmaf(a.z, w.z, acc2.z); acc2.w = fmaf(a.z, w.w, acc2.w);
        acc3.x = fmaf(a.w, w.x, acc3.x); acc3.y = fmaf(a.w, w.y, acc3.y);
        acc3.z = fmaf(a.w, w.z, acc3.z); acc3.w = fmaf(a.w, w.w, acc3.w);
    }
    if (bias) {
        float4 b = *(const float4*)&bias[jc];
        acc0.x += b.x; acc0.y += b.y; acc0.z += b.z; acc0.w += b.w;
        acc1.x += b.x; acc1.y += b.y; acc1.z += b.z; acc1.w += b.w;
        acc2.x += b.x; acc2.y += b.y; acc2.z += b.z; acc2.w += b.w;
        acc3.x += b.x; acc3.y += b.y; acc3.z += b.z; acc3.w += b.w;
    }
    *(float4*)&out[(size_t)(row0 + rc + 0) * NC + jc] = acc0;
    *(float4*)&out[(size_t)(row0 + rc + 1) * NC + jc] = acc1;
    *(float4*)&out[(size_t)(row0 + rc + 2) * NC + jc] = acc2;
    *(float4*)&out[(size_t)(row0 + rc + 3) * NC + jc] = acc3;
}

extern "C" void kernel_launch(void* const* d_in, const int* in_sizes, int n_in,
                              void* d_out, int out_size, void* d_ws, size_t ws_size,
                              hipStream_t stream) {
    const float* emb = (const float*)d_in[0];   // [50000][128]
    const float* W1  = (const float*)d_in[1];   // [128][256]
    const float* b1  = (const float*)d_in[2];   // [256]
    const float* W2  = (const float*)d_in[3];   // [256][128]
    const float* b2  = (const float*)d_in[4];   // [128]
    const int*   ei  = (const int*)d_in[5];     // [2][800000]
    const int* src = ei;
    const int* dst = ei + N_EDGES;

    char* ws = (char*)d_ws;
    float* dinv    = (float*)(ws);                    // 200 KB
    int*   counts  = (int*)  (ws + (256ull << 10));   // 200 KB
    int*   row_ptr = (int*)  (ws + (512ull << 10));   // 200 KB + 4
    int*   fill    = (int*)  (ws + (768ull << 10));   // 200 KB
    int*   bsum    = (int*)  (ws + (1008ull << 10));  // 784 B
    int*   boff    = (int*)  (ws + (1016ull << 10));  // 784 B
    int*   csr_src = (int*)  (ws + (1ull   << 20));   // 3.2 MB
    float* agg0    = (float*)(ws + (8ull   << 20));   // 25.6 MB
    float* h       = (float*)(ws + (40ull  << 20));   // 51.2 MB
    float* x2      = agg0;                            // reuse: agg0 dead after GEMM1
    float* out     = (float*)d_out;

    // CSR build + normalization (device-wide 3-stage scan)
    k_zero<<<NB, 256, 0, stream>>>(counts);
    k_hist<<<(N_EDGES + 255) / 256, 256, 0, stream>>>(dst, counts);
    k_blocksum<<<NB, 256, 0, stream>>>(counts, bsum);
    k_scanb<<<1, 256, 0, stream>>>(bsum, boff);
    k_scatter_rp<<<NB, 256, 0, stream>>>(counts, boff, row_ptr, fill, dinv);
    k_fill<<<(N_EDGES + 255) / 256, 256, 0, stream>>>(src, dst, fill, csr_src);

    // layer 1 (reordered): agg0 = Agg(emb); h = agg0 @ W1 + b1
    k_gather128<<<12500, 256, 0, stream>>>(emb, csr_src, row_ptr, dinv, nullptr, agg0);
    k_gemm<128, 256><<<N_NODES / 16, 256, 0, stream>>>(agg0, W1, b1, h);

    // layer 2: x2 = h @ W2 ; out = Agg(x2) + b2
    k_gemm<256, 128><<<N_NODES / 16, 128, 0, stream>>>(h, W2, nullptr, x2);
    k_gather128<<<12500, 256, 0, stream>>>(x2, csr_src, row_ptr, dinv, b2, out);
}

// Round 4
// 324.306 us; speedup vs baseline: 12.9406x; 1.2326x over previous
//
#include <hip/hip_runtime.h>

#define N_NODES 50000
#define N_EDGES 800000
#define NB 196  // ceil(N_NODES / 256)

// ---------- degree / CSR build ----------

__global__ void k_zero(int* counts) {
    int i = blockIdx.x * 256 + threadIdx.x;
    if (i < N_NODES) counts[i] = 0;
}

__global__ void k_hist(const int* __restrict__ dst, int* __restrict__ counts) {
    int e = blockIdx.x * 256 + threadIdx.x;
    if (e < N_EDGES) atomicAdd(&counts[dst[e]], 1);
}

__global__ void k_blocksum(const int* __restrict__ counts, int* __restrict__ bsum) {
    __shared__ int lds[256];
    int t = threadIdx.x;
    int i = blockIdx.x * 256 + t;
    int v = (i < N_NODES) ? counts[i] : 0;
    lds[t] = v;
    __syncthreads();
    for (int off = 128; off > 0; off >>= 1) {
        if (t < off) lds[t] += lds[t + off];
        __syncthreads();
    }
    if (t == 0) bsum[blockIdx.x] = lds[0];
}

__global__ void k_scanb(const int* __restrict__ bsum, int* __restrict__ boff) {
    __shared__ int lds[256];
    int t = threadIdx.x;
    int v = (t < NB) ? bsum[t] : 0;
    lds[t] = v;
    __syncthreads();
    for (int off = 1; off < 256; off <<= 1) {
        int o = (t >= off) ? lds[t - off] : 0;
        __syncthreads();
        lds[t] += o;
        __syncthreads();
    }
    if (t < NB) boff[t] = lds[t] - v;  // exclusive
}

__global__ void k_scatter_rp(const int* __restrict__ counts, const int* __restrict__ boff,
                             int* __restrict__ row_ptr, int* __restrict__ fill,
                             float* __restrict__ dinv) {
    __shared__ int lds[256];
    int t = threadIdx.x;
    int i = blockIdx.x * 256 + t;
    int v = (i < N_NODES) ? counts[i] : 0;
    lds[t] = v;
    __syncthreads();
    for (int off = 1; off < 256; off <<= 1) {
        int o = (t >= off) ? lds[t - off] : 0;
        __syncthreads();
        lds[t] += o;
        __syncthreads();
    }
    if (i < N_NODES) {
        int excl = boff[blockIdx.x] + lds[t] - v;
        row_ptr[i] = excl;
        fill[i] = excl;
        dinv[i] = rsqrtf((float)(v + 1));  // +1 self-loop
    }
    if (i == 0) row_ptr[N_NODES] = N_EDGES;
}

__global__ void k_fill(const int* __restrict__ src, const int* __restrict__ dst,
                       int* __restrict__ fill, int* __restrict__ csr_src) {
    int e = blockIdx.x * 256 + threadIdx.x;
    if (e >= N_EDGES) return;
    int pos = atomicAdd(&fill[dst[e]], 1);
    csr_src[pos] = src[e];
}

// ---------- gather aggregation (F=128, one wave per dst node) ----------
// 4 quarter-waves x 2-deep unroll = 8 source rows in flight per wave.
// Each quarter (16 lanes) covers the full 128-float row: lane fl -> floats [fl*8, fl*8+8).
__global__ void k_gather128(const float* __restrict__ x, const int* __restrict__ csr,
                            const int* __restrict__ rp, const float* __restrict__ dinv,
                            const float* __restrict__ bias, float* __restrict__ out) {
    int node = blockIdx.x * 4 + (threadIdx.x >> 6);
    int lane = threadIdx.x & 63;
    int q = lane >> 4;
    int fl = lane & 15;
    int beg = rp[node], end = rp[node + 1];
    const float4* xb = (const float4*)x;  // row s = 32 float4s
    float4 a0 = {0,0,0,0}, a1 = {0,0,0,0};
    for (int j = beg + q; j < end; j += 8) {
        int s0 = csr[j];
        float c0 = dinv[s0];
        const float4* r0 = xb + (size_t)s0 * 32 + fl * 2;
        float4 u0 = r0[0];
        float4 u1 = r0[1];
        int j1 = j + 4;
        int s1 = s0;
        float c1 = 0.f;
        if (j1 < end) { s1 = csr[j1]; c1 = dinv[s1]; }
        const float4* r1 = xb + (size_t)s1 * 32 + fl * 2;
        float4 w0 = r1[0];
        float4 w1 = r1[1];
        a0.x = fmaf(c0, u0.x, a0.x); a0.y = fmaf(c0, u0.y, a0.y);
        a0.z = fmaf(c0, u0.z, a0.z); a0.w = fmaf(c0, u0.w, a0.w);
        a1.x = fmaf(c0, u1.x, a1.x); a1.y = fmaf(c0, u1.y, a1.y);
        a1.z = fmaf(c0, u1.z, a1.z); a1.w = fmaf(c0, u1.w, a1.w);
        a0.x = fmaf(c1, w0.x, a0.x); a0.y = fmaf(c1, w0.y, a0.y);
        a0.z = fmaf(c1, w0.z, a0.z); a0.w = fmaf(c1, w0.w, a0.w);
        a1.x = fmaf(c1, w1.x, a1.x); a1.y = fmaf(c1, w1.y, a1.y);
        a1.z = fmaf(c1, w1.z, a1.z); a1.w = fmaf(c1, w1.w, a1.w);
    }
    // reduce across the 4 quarter-waves (feature slots align: lane&15)
    #pragma unroll
    for (int off = 16; off < 64; off <<= 1) {
        a0.x += __shfl_xor(a0.x, off); a0.y += __shfl_xor(a0.y, off);
        a0.z += __shfl_xor(a0.z, off); a0.w += __shfl_xor(a0.w, off);
        a1.x += __shfl_xor(a1.x, off); a1.y += __shfl_xor(a1.y, off);
        a1.z += __shfl_xor(a1.z, off); a1.w += __shfl_xor(a1.w, off);
    }
    if (q == 0) {
        float dd = dinv[node];
        float dd2 = dd * dd;
        const float4* sr = xb + (size_t)node * 32 + fl * 2;
        float4 s0 = sr[0], s1 = sr[1];
        float4 o0, o1;
        o0.x = fmaf(dd, a0.x, dd2 * s0.x); o0.y = fmaf(dd, a0.y, dd2 * s0.y);
        o0.z = fmaf(dd, a0.z, dd2 * s0.z); o0.w = fmaf(dd, a0.w, dd2 * s0.w);
        o1.x = fmaf(dd, a1.x, dd2 * s1.x); o1.y = fmaf(dd, a1.y, dd2 * s1.y);
        o1.z = fmaf(dd, a1.z, dd2 * s1.z); o1.w = fmaf(dd, a1.w, dd2 * s1.w);
        if (bias) {
            const float4* bb = (const float4*)bias;
            float4 b0 = bb[fl * 2], b1 = bb[fl * 2 + 1];
            o0.x += b0.x; o0.y += b0.y; o0.z += b0.z; o0.w += b0.w;
            o1.x += b1.x; o1.y += b1.y; o1.z += b1.z; o1.w += b1.w;
        }
        float4* ob = (float4*)out + (size_t)node * 32 + fl * 2;
        ob[0] = o0;
        ob[1] = o1;
    }
}

// ---------- GEMM: out[RPB rows][NC] = A[RPB][K] @ W[K][NC] (+ bias) ----------
// Micro-tile: MR rows x 4 cols per thread. NT = (NC/4)*(RPB/MR) threads.
template<int K, int NC, int RPB, int MR>
__global__ void k_gemm(const float* __restrict__ A, const float* __restrict__ W,
                       const float* __restrict__ bias, float* __restrict__ out) {
    constexpr int NT = (NC / 4) * (RPB / MR);
    constexpr int LSTR = RPB + 4;
    __shared__ float lds[K * LSTR];
    const int row0 = blockIdx.x * RPB;
    const int t = threadIdx.x;

    // Stage A tile transposed: lds[k][r]; coalesced float4 global reads.
    constexpr int TOT4 = K * RPB / 4;
    #pragma unroll
    for (int i = 0; i < TOT4 / NT; ++i) {
        int c = i * NT + t;
        int r = c / (K / 4), k4 = c % (K / 4);
        int rg = row0 + r;
        if (rg > N_NODES - 1) rg = N_NODES - 1;  // tail clamp (50000 % RPB != 0)
        float4 v = *(const float4*)&A[(size_t)rg * K + k4 * 4];
        lds[(k4 * 4 + 0) * LSTR + r] = v.x;
        lds[(k4 * 4 + 1) * LSTR + r] = v.y;
        lds[(k4 * 4 + 2) * LSTR + r] = v.z;
        lds[(k4 * 4 + 3) * LSTR + r] = v.w;
    }
    __syncthreads();

    const int jc = (t % (NC / 4)) * 4;
    const int rc = (t / (NC / 4)) * MR;
    float4 acc[MR];
    #pragma unroll
    for (int m = 0; m < MR; ++m) acc[m] = make_float4(0.f, 0.f, 0.f, 0.f);

    #pragma unroll 4
    for (int k = 0; k < K; ++k) {
        float4 w = *(const float4*)&W[k * NC + jc];
        #pragma unroll
        for (int mb = 0; mb < MR; mb += 4) {
            float4 a = *(const float4*)&lds[k * LSTR + rc + mb];
            acc[mb + 0].x = fmaf(a.x, w.x, acc[mb + 0].x);
            acc[mb + 0].y = fmaf(a.x, w.y, acc[mb + 0].y);
            acc[mb + 0].z = fmaf(a.x, w.z, acc[mb + 0].z);
            acc[mb + 0].w = fmaf(a.x, w.w, acc[mb + 0].w);
            acc[mb + 1].x = fmaf(a.y, w.x, acc[mb + 1].x);
            acc[mb + 1].y = fmaf(a.y, w.y, acc[mb + 1].y);
            acc[mb + 1].z = fmaf(a.y, w.z, acc[mb + 1].z);
            acc[mb + 1].w = fmaf(a.y, w.w, acc[mb + 1].w);
            acc[mb + 2].x = fmaf(a.z, w.x, acc[mb + 2].x);
            acc[mb + 2].y = fmaf(a.z, w.y, acc[mb + 2].y);
            acc[mb + 2].z = fmaf(a.z, w.z, acc[mb + 2].z);
            acc[mb + 2].w = fmaf(a.z, w.w, acc[mb + 2].w);
            acc[mb + 3].x = fmaf(a.w, w.x, acc[mb + 3].x);
            acc[mb + 3].y = fmaf(a.w, w.y, acc[mb + 3].y);
            acc[mb + 3].z = fmaf(a.w, w.z, acc[mb + 3].z);
            acc[mb + 3].w = fmaf(a.w, w.w, acc[mb + 3].w);
        }
    }

    float4 b = make_float4(0.f, 0.f, 0.f, 0.f);
    if (bias) b = *(const float4*)&bias[jc];
    #pragma unroll
    for (int m = 0; m < MR; ++m) {
        int r = row0 + rc + m;
        if (r < N_NODES) {
            float4 o = acc[m];
            o.x += b.x; o.y += b.y; o.z += b.z; o.w += b.w;
            *(float4*)&out[(size_t)r * NC + jc] = o;
        }
    }
}

extern "C" void kernel_launch(void* const* d_in, const int* in_sizes, int n_in,
                              void* d_out, int out_size, void* d_ws, size_t ws_size,
                              hipStream_t stream) {
    const float* emb = (const float*)d_in[0];   // [50000][128]
    const float* W1  = (const float*)d_in[1];   // [128][256]
    const float* b1  = (const float*)d_in[2];   // [256]
    const float* W2  = (const float*)d_in[3];   // [256][128]
    const float* b2  = (const float*)d_in[4];   // [128]
    const int*   ei  = (const int*)d_in[5];     // [2][800000]
    const int* src = ei;
    const int* dst = ei + N_EDGES;

    char* ws = (char*)d_ws;
    float* dinv    = (float*)(ws);                    // 200 KB
    int*   counts  = (int*)  (ws + (256ull << 10));   // 200 KB
    int*   row_ptr = (int*)  (ws + (512ull << 10));   // 200 KB + 4
    int*   fill    = (int*)  (ws + (768ull << 10));   // 200 KB
    int*   bsum    = (int*)  (ws + (1008ull << 10));  // 784 B
    int*   boff    = (int*)  (ws + (1016ull << 10));  // 784 B
    int*   csr_src = (int*)  (ws + (1ull   << 20));   // 3.2 MB
    float* agg0    = (float*)(ws + (8ull   << 20));   // 25.6 MB
    float* h       = (float*)(ws + (40ull  << 20));   // 51.2 MB
    float* x2      = agg0;                            // reuse: agg0 dead after GEMM1
    float* out     = (float*)d_out;

    // CSR build + normalization (device-wide 3-stage scan)
    k_zero<<<NB, 256, 0, stream>>>(counts);
    k_hist<<<(N_EDGES + 255) / 256, 256, 0, stream>>>(dst, counts);
    k_blocksum<<<NB, 256, 0, stream>>>(counts, bsum);
    k_scanb<<<1, 256, 0, stream>>>(bsum, boff);
    k_scatter_rp<<<NB, 256, 0, stream>>>(counts, boff, row_ptr, fill, dinv);
    k_fill<<<(N_EDGES + 255) / 256, 256, 0, stream>>>(src, dst, fill, csr_src);

    // layer 1 (reordered): agg0 = Agg(emb); h = agg0 @ W1 + b1
    k_gather128<<<12500, 256, 0, stream>>>(emb, csr_src, row_ptr, dinv, nullptr, agg0);
    k_gemm<128, 256, 32, 8><<<(N_NODES + 31) / 32, 256, 0, stream>>>(agg0, W1, b1, h);

    // layer 2: x2 = h @ W2 ; out = Agg(x2) + b2
    k_gemm<256, 128, 32, 4><<<(N_NODES + 31) / 32, 256, 0, stream>>>(h, W2, nullptr, x2);
    k_gather128<<<12500, 256, 0, stream>>>(x2, csr_src, row_ptr, dinv, b2, out);
}

// Round 5
// 317.696 us; speedup vs baseline: 13.2098x; 1.0208x over previous
//
#include <hip/hip_runtime.h>

#define N_NODES 50000
#define N_EDGES 800000
#define NB 196  // ceil(N_NODES / 256)

// ---------- degree / CSR build ----------

__global__ void k_zero(int* counts) {
    int i = blockIdx.x * 256 + threadIdx.x;
    if (i < N_NODES) counts[i] = 0;
}

__global__ void k_hist(const int* __restrict__ dst, int* __restrict__ counts) {
    int e = blockIdx.x * 256 + threadIdx.x;
    if (e < N_EDGES) atomicAdd(&counts[dst[e]], 1);
}

__global__ void k_blocksum(const int* __restrict__ counts, int* __restrict__ bsum) {
    __shared__ int lds[256];
    int t = threadIdx.x;
    int i = blockIdx.x * 256 + t;
    int v = (i < N_NODES) ? counts[i] : 0;
    lds[t] = v;
    __syncthreads();
    for (int off = 128; off > 0; off >>= 1) {
        if (t < off) lds[t] += lds[t + off];
        __syncthreads();
    }
    if (t == 0) bsum[blockIdx.x] = lds[0];
}

__global__ void k_scanb(const int* __restrict__ bsum, int* __restrict__ boff) {
    __shared__ int lds[256];
    int t = threadIdx.x;
    int v = (t < NB) ? bsum[t] : 0;
    lds[t] = v;
    __syncthreads();
    for (int off = 1; off < 256; off <<= 1) {
        int o = (t >= off) ? lds[t - off] : 0;
        __syncthreads();
        lds[t] += o;
        __syncthreads();
    }
    if (t < NB) boff[t] = lds[t] - v;  // exclusive
}

__global__ void k_scatter_rp(const int* __restrict__ counts, const int* __restrict__ boff,
                             int* __restrict__ row_ptr, int* __restrict__ fill,
                             float* __restrict__ dinv) {
    __shared__ int lds[256];
    int t = threadIdx.x;
    int i = blockIdx.x * 256 + t;
    int v = (i < N_NODES) ? counts[i] : 0;
    lds[t] = v;
    __syncthreads();
    for (int off = 1; off < 256; off <<= 1) {
        int o = (t >= off) ? lds[t - off] : 0;
        __syncthreads();
        lds[t] += o;
        __syncthreads();
    }
    if (i < N_NODES) {
        int excl = boff[blockIdx.x] + lds[t] - v;
        row_ptr[i] = excl;
        fill[i] = excl;
        dinv[i] = rsqrtf((float)(v + 1));  // +1 self-loop
    }
    if (i == 0) row_ptr[N_NODES] = N_EDGES;
}

__global__ void k_fill(const int* __restrict__ src, const int* __restrict__ dst,
                       int* __restrict__ fill, int* __restrict__ csr_src) {
    int e = blockIdx.x * 256 + threadIdx.x;
    if (e >= N_EDGES) return;
    int pos = atomicAdd(&fill[dst[e]], 1);
    csr_src[pos] = src[e];
}

// ---------- gather aggregation (F=128, one wave per dst node) ----------
// 4 quarter-waves x 2-deep unroll = 8 source rows in flight per wave.
__global__ void k_gather128(const float* __restrict__ x, const int* __restrict__ csr,
                            const int* __restrict__ rp, const float* __restrict__ dinv,
                            const float* __restrict__ bias, float* __restrict__ out) {
    int node = blockIdx.x * 4 + (threadIdx.x >> 6);
    int lane = threadIdx.x & 63;
    int q = lane >> 4;
    int fl = lane & 15;
    int beg = rp[node], end = rp[node + 1];
    const float4* xb = (const float4*)x;  // row s = 32 float4s
    float4 a0 = {0,0,0,0}, a1 = {0,0,0,0};
    for (int j = beg + q; j < end; j += 8) {
        int s0 = csr[j];
        float c0 = dinv[s0];
        const float4* r0 = xb + (size_t)s0 * 32 + fl * 2;
        float4 u0 = r0[0];
        float4 u1 = r0[1];
        int j1 = j + 4;
        int s1 = s0;
        float c1 = 0.f;
        if (j1 < end) { s1 = csr[j1]; c1 = dinv[s1]; }
        const float4* r1 = xb + (size_t)s1 * 32 + fl * 2;
        float4 w0 = r1[0];
        float4 w1 = r1[1];
        a0.x = fmaf(c0, u0.x, a0.x); a0.y = fmaf(c0, u0.y, a0.y);
        a0.z = fmaf(c0, u0.z, a0.z); a0.w = fmaf(c0, u0.w, a0.w);
        a1.x = fmaf(c0, u1.x, a1.x); a1.y = fmaf(c0, u1.y, a1.y);
        a1.z = fmaf(c0, u1.z, a1.z); a1.w = fmaf(c0, u1.w, a1.w);
        a0.x = fmaf(c1, w0.x, a0.x); a0.y = fmaf(c1, w0.y, a0.y);
        a0.z = fmaf(c1, w0.z, a0.z); a0.w = fmaf(c1, w0.w, a0.w);
        a1.x = fmaf(c1, w1.x, a1.x); a1.y = fmaf(c1, w1.y, a1.y);
        a1.z = fmaf(c1, w1.z, a1.z); a1.w = fmaf(c1, w1.w, a1.w);
    }
    #pragma unroll
    for (int off = 16; off < 64; off <<= 1) {
        a0.x += __shfl_xor(a0.x, off); a0.y += __shfl_xor(a0.y, off);
        a0.z += __shfl_xor(a0.z, off); a0.w += __shfl_xor(a0.w, off);
        a1.x += __shfl_xor(a1.x, off); a1.y += __shfl_xor(a1.y, off);
        a1.z += __shfl_xor(a1.z, off); a1.w += __shfl_xor(a1.w, off);
    }
    if (q == 0) {
        float dd = dinv[node];
        float dd2 = dd * dd;
        const float4* sr = xb + (size_t)node * 32 + fl * 2;
        float4 s0 = sr[0], s1 = sr[1];
        float4 o0, o1;
        o0.x = fmaf(dd, a0.x, dd2 * s0.x); o0.y = fmaf(dd, a0.y, dd2 * s0.y);
        o0.z = fmaf(dd, a0.z, dd2 * s0.z); o0.w = fmaf(dd, a0.w, dd2 * s0.w);
        o1.x = fmaf(dd, a1.x, dd2 * s1.x); o1.y = fmaf(dd, a1.y, dd2 * s1.y);
        o1.z = fmaf(dd, a1.z, dd2 * s1.z); o1.w = fmaf(dd, a1.w, dd2 * s1.w);
        if (bias) {
            const float4* bb = (const float4*)bias;
            float4 b0 = bb[fl * 2], b1 = bb[fl * 2 + 1];
            o0.x += b0.x; o0.y += b0.y; o0.z += b0.z; o0.w += b0.w;
            o1.x += b1.x; o1.y += b1.y; o1.z += b1.z; o1.w += b1.w;
        }
        float4* ob = (float4*)out + (size_t)node * 32 + fl * 2;
        ob[0] = o0;
        ob[1] = o1;
    }
}

// ---------- GEMM: out[RPB rows][NC] = A[RPB][K] @ W[K][NC] (+ bias) ----------
// A staged row-major [RPB][BK] in LDS (float4 writes, conflict-free;
// reads are wave-broadcast -> conflict-free, no padding needed).
// Thread = 4 cols (jc) x MR rows (rc). NT = (NC/4)*(RPB/MR).
template<int K, int NC, int RPB, int MR, int BK>
__global__ void k_gemm(const float* __restrict__ A, const float* __restrict__ W,
                       const float* __restrict__ bias, float* __restrict__ out) {
    constexpr int NT = (NC / 4) * (RPB / MR);
    __shared__ float lds[RPB][BK];
    const int row0 = blockIdx.x * RPB;
    const int t = threadIdx.x;
    const int jc = (t % (NC / 4)) * 4;
    const int rc = (t / (NC / 4)) * MR;

    float4 acc[MR];
    #pragma unroll
    for (int m = 0; m < MR; ++m) acc[m] = make_float4(0.f, 0.f, 0.f, 0.f);

    for (int k0 = 0; k0 < K; k0 += BK) {
        if (k0 > 0) __syncthreads();  // protect LDS reuse across chunks
        constexpr int QUADS = RPB * BK / 4;
        #pragma unroll
        for (int i = 0; i < QUADS / NT; ++i) {
            int idx = i * NT + t;
            int r = idx / (BK / 4), k4 = idx % (BK / 4);
            int rg = row0 + r;
            if (rg >= N_NODES) rg = N_NODES - 1;  // tail clamp
            *(float4*)&lds[r][k4 * 4] = *(const float4*)&A[(size_t)rg * K + k0 + k4 * 4];
        }
        __syncthreads();

        #pragma unroll 2
        for (int kk = 0; kk < BK; kk += 4) {
            const float* wr = &W[(size_t)(k0 + kk) * NC + jc];
            float4 w0 = *(const float4*)(wr);
            float4 w1 = *(const float4*)(wr + NC);
            float4 w2 = *(const float4*)(wr + 2 * NC);
            float4 w3 = *(const float4*)(wr + 3 * NC);
            #pragma unroll
            for (int m = 0; m < MR; ++m) {
                float4 a = *(const float4*)&lds[rc + m][kk];  // broadcast
                acc[m].x = fmaf(a.x, w0.x, acc[m].x);
                acc[m].y = fmaf(a.x, w0.y, acc[m].y);
                acc[m].z = fmaf(a.x, w0.z, acc[m].z);
                acc[m].w = fmaf(a.x, w0.w, acc[m].w);
                acc[m].x = fmaf(a.y, w1.x, acc[m].x);
                acc[m].y = fmaf(a.y, w1.y, acc[m].y);
                acc[m].z = fmaf(a.y, w1.z, acc[m].z);
                acc[m].w = fmaf(a.y, w1.w, acc[m].w);
                acc[m].x = fmaf(a.z, w2.x, acc[m].x);
                acc[m].y = fmaf(a.z, w2.y, acc[m].y);
                acc[m].z = fmaf(a.z, w2.z, acc[m].z);
                acc[m].w = fmaf(a.z, w2.w, acc[m].w);
                acc[m].x = fmaf(a.w, w3.x, acc[m].x);
                acc[m].y = fmaf(a.w, w3.y, acc[m].y);
                acc[m].z = fmaf(a.w, w3.z, acc[m].z);
                acc[m].w = fmaf(a.w, w3.w, acc[m].w);
            }
        }
    }

    float4 b = make_float4(0.f, 0.f, 0.f, 0.f);
    if (bias) b = *(const float4*)&bias[jc];
    #pragma unroll
    for (int m = 0; m < MR; ++m) {
        int r = row0 + rc + m;
        if (r < N_NODES) {
            float4 o = acc[m];
            o.x += b.x; o.y += b.y; o.z += b.z; o.w += b.w;
            *(float4*)&out[(size_t)r * NC + jc] = o;
        }
    }
}

extern "C" void kernel_launch(void* const* d_in, const int* in_sizes, int n_in,
                              void* d_out, int out_size, void* d_ws, size_t ws_size,
                              hipStream_t stream) {
    const float* emb = (const float*)d_in[0];   // [50000][128]
    const float* W1  = (const float*)d_in[1];   // [128][256]
    const float* b1  = (const float*)d_in[2];   // [256]
    const float* W2  = (const float*)d_in[3];   // [256][128]
    const float* b2  = (const float*)d_in[4];   // [128]
    const int*   ei  = (const int*)d_in[5];     // [2][800000]
    const int* src = ei;
    const int* dst = ei + N_EDGES;

    char* ws = (char*)d_ws;
    float* dinv    = (float*)(ws);                    // 200 KB
    int*   counts  = (int*)  (ws + (256ull << 10));   // 200 KB
    int*   row_ptr = (int*)  (ws + (512ull << 10));   // 200 KB + 4
    int*   fill    = (int*)  (ws + (768ull << 10));   // 200 KB
    int*   bsum    = (int*)  (ws + (1008ull << 10));  // 784 B
    int*   boff    = (int*)  (ws + (1016ull << 10));  // 784 B
    int*   csr_src = (int*)  (ws + (1ull   << 20));   // 3.2 MB
    float* agg0    = (float*)(ws + (8ull   << 20));   // 25.6 MB
    float* h       = (float*)(ws + (40ull  << 20));   // 51.2 MB
    float* x2      = agg0;                            // reuse: agg0 dead after GEMM1
    float* out     = (float*)d_out;

    // CSR build + normalization (device-wide 3-stage scan)
    k_zero<<<NB, 256, 0, stream>>>(counts);
    k_hist<<<(N_EDGES + 255) / 256, 256, 0, stream>>>(dst, counts);
    k_blocksum<<<NB, 256, 0, stream>>>(counts, bsum);
    k_scanb<<<1, 256, 0, stream>>>(bsum, boff);
    k_scatter_rp<<<NB, 256, 0, stream>>>(counts, boff, row_ptr, fill, dinv);
    k_fill<<<(N_EDGES + 255) / 256, 256, 0, stream>>>(src, dst, fill, csr_src);

    // layer 1 (reordered): agg0 = Agg(emb); h = agg0 @ W1 + b1
    k_gather128<<<12500, 256, 0, stream>>>(emb, csr_src, row_ptr, dinv, nullptr, agg0);
    // K=128 NC=256 RPB=64 MR=8 BK=128 -> 512 threads, 32KB LDS
    k_gemm<128, 256, 64, 8, 128><<<(N_NODES + 63) / 64, 512, 0, stream>>>(agg0, W1, b1, h);

    // layer 2: x2 = h @ W2 ; out = Agg(x2) + b2
    // K=256 NC=128 RPB=64 MR=8 BK=128 -> 256 threads, 32KB LDS
    k_gemm<256, 128, 64, 8, 128><<<(N_NODES + 63) / 64, 256, 0, stream>>>(h, W2, nullptr, x2);
    k_gather128<<<12500, 256, 0, stream>>>(x2, csr_src, row_ptr, dinv, b2, out);
}

// Round 6
// 281.526 us; speedup vs baseline: 14.9070x; 1.1285x over previous
//
#include <hip/hip_runtime.h>

#define N_NODES 50000
#define N_EDGES 800000
#define NB 196  // ceil(N_NODES / 256)

typedef unsigned int uint;

__device__ __forceinline__ ushort f2bf(float f) {
    union { float f; uint u; } v; v.f = f;
    uint r = (v.u + 0x7FFFu + ((v.u >> 16) & 1u)) >> 16;  // RNE
    return (ushort)r;
}
__device__ __forceinline__ float bf_lo(uint u) { return __uint_as_float(u << 16); }
__device__ __forceinline__ float bf_hi(uint u) { return __uint_as_float(u & 0xFFFF0000u); }

// ---------- fp32 -> bf16 table conversion (8 floats/thread) ----------
__global__ void k_tobf16(const float* __restrict__ in, uint* __restrict__ out) {
    int t = blockIdx.x * 256 + threadIdx.x;      // over N*128/8 groups
    const float4* i4 = (const float4*)in + (size_t)t * 2;
    float4 v0 = i4[0], v1 = i4[1];
    uint4 o;
    o.x = (uint)f2bf(v0.x) | ((uint)f2bf(v0.y) << 16);
    o.y = (uint)f2bf(v0.z) | ((uint)f2bf(v0.w) << 16);
    o.z = (uint)f2bf(v1.x) | ((uint)f2bf(v1.y) << 16);
    o.w = (uint)f2bf(v1.z) | ((uint)f2bf(v1.w) << 16);
    ((uint4*)out)[t] = o;
}

// ---------- degree / CSR build ----------

__global__ void k_zero(int* counts) {
    int i = blockIdx.x * 256 + threadIdx.x;
    if (i < N_NODES) counts[i] = 0;
}

__global__ void k_hist(const int* __restrict__ dst, int* __restrict__ counts) {
    int e = blockIdx.x * 256 + threadIdx.x;
    if (e < N_EDGES) atomicAdd(&counts[dst[e]], 1);
}

__global__ void k_blocksum(const int* __restrict__ counts, int* __restrict__ bsum) {
    __shared__ int lds[256];
    int t = threadIdx.x;
    int i = blockIdx.x * 256 + t;
    int v = (i < N_NODES) ? counts[i] : 0;
    lds[t] = v;
    __syncthreads();
    for (int off = 128; off > 0; off >>= 1) {
        if (t < off) lds[t] += lds[t + off];
        __syncthreads();
    }
    if (t == 0) bsum[blockIdx.x] = lds[0];
}

__global__ void k_scanb(const int* __restrict__ bsum, int* __restrict__ boff) {
    __shared__ int lds[256];
    int t = threadIdx.x;
    int v = (t < NB) ? bsum[t] : 0;
    lds[t] = v;
    __syncthreads();
    for (int off = 1; off < 256; off <<= 1) {
        int o = (t >= off) ? lds[t - off] : 0;
        __syncthreads();
        lds[t] += o;
        __syncthreads();
    }
    if (t < NB) boff[t] = lds[t] - v;  // exclusive
}

__global__ void k_scatter_rp(const int* __restrict__ counts, const int* __restrict__ boff,
                             int* __restrict__ row_ptr, int* __restrict__ fill,
                             float* __restrict__ dinv) {
    __shared__ int lds[256];
    int t = threadIdx.x;
    int i = blockIdx.x * 256 + t;
    int v = (i < N_NODES) ? counts[i] : 0;
    lds[t] = v;
    __syncthreads();
    for (int off = 1; off < 256; off <<= 1) {
        int o = (t >= off) ? lds[t - off] : 0;
        __syncthreads();
        lds[t] += o;
        __syncthreads();
    }
    if (i < N_NODES) {
        int excl = boff[blockIdx.x] + lds[t] - v;
        row_ptr[i] = excl;
        fill[i] = excl;
        dinv[i] = rsqrtf((float)(v + 1));  // +1 self-loop
    }
    if (i == 0) row_ptr[N_NODES] = N_EDGES;
}

__global__ void k_fill(const int* __restrict__ src, const int* __restrict__ dst,
                       int* __restrict__ fill, int* __restrict__ csr_src) {
    int e = blockIdx.x * 256 + threadIdx.x;
    if (e >= N_EDGES) return;
    int pos = atomicAdd(&fill[dst[e]], 1);
    csr_src[pos] = src[e];
}

// ---------- gather aggregation over bf16 table (F=128, one wave per dst) ----------
// Row = 128 bf16 = 16 uint4s. Quarter-wave q handles neighbors j = beg+q, +8, ...
// (2-deep unroll -> 8 rows in flight per wave). Lane fl covers feats [fl*8, fl*8+8).
__global__ void k_gather128h(const uint* __restrict__ xh, const int* __restrict__ csr,
                             const int* __restrict__ rp, const float* __restrict__ dinv,
                             const float* __restrict__ bias, float* __restrict__ out) {
    int node = blockIdx.x * 4 + (threadIdx.x >> 6);
    int lane = threadIdx.x & 63;
    int q = lane >> 4;
    int fl = lane & 15;
    int beg = rp[node], end = rp[node + 1];
    const uint4* xb = (const uint4*)xh;  // row s = 16 uint4s
    float a[8];
    #pragma unroll
    for (int i = 0; i < 8; ++i) a[i] = 0.f;

    for (int j = beg + q; j < end; j += 8) {
        int s0 = csr[j];
        float c0 = dinv[s0];
        uint4 u = xb[(size_t)s0 * 16 + fl];
        int j1 = j + 4;
        int s1 = s0;
        float c1 = 0.f;
        if (j1 < end) { s1 = csr[j1]; c1 = dinv[s1]; }
        uint4 w = xb[(size_t)s1 * 16 + fl];
        a[0] = fmaf(c0, bf_lo(u.x), a[0]); a[1] = fmaf(c0, bf_hi(u.x), a[1]);
        a[2] = fmaf(c0, bf_lo(u.y), a[2]); a[3] = fmaf(c0, bf_hi(u.y), a[3]);
        a[4] = fmaf(c0, bf_lo(u.z), a[4]); a[5] = fmaf(c0, bf_hi(u.z), a[5]);
        a[6] = fmaf(c0, bf_lo(u.w), a[6]); a[7] = fmaf(c0, bf_hi(u.w), a[7]);
        a[0] = fmaf(c1, bf_lo(w.x), a[0]); a[1] = fmaf(c1, bf_hi(w.x), a[1]);
        a[2] = fmaf(c1, bf_lo(w.y), a[2]); a[3] = fmaf(c1, bf_hi(w.y), a[3]);
        a[4] = fmaf(c1, bf_lo(w.z), a[4]); a[5] = fmaf(c1, bf_hi(w.z), a[5]);
        a[6] = fmaf(c1, bf_lo(w.w), a[6]); a[7] = fmaf(c1, bf_hi(w.w), a[7]);
    }
    #pragma unroll
    for (int off = 16; off < 64; off <<= 1) {
        #pragma unroll
        for (int i = 0; i < 8; ++i) a[i] += __shfl_xor(a[i], off);
    }
    if (q == 0) {
        float dd = dinv[node];
        float dd2 = dd * dd;
        uint4 u = xb[(size_t)node * 16 + fl];
        float s[8] = { bf_lo(u.x), bf_hi(u.x), bf_lo(u.y), bf_hi(u.y),
                       bf_lo(u.z), bf_hi(u.z), bf_lo(u.w), bf_hi(u.w) };
        float o[8];
        #pragma unroll
        for (int i = 0; i < 8; ++i) o[i] = fmaf(dd, a[i], dd2 * s[i]);
        if (bias) {
            const float4* bb = (const float4*)bias;
            float4 b0 = bb[fl * 2], b1 = bb[fl * 2 + 1];
            o[0] += b0.x; o[1] += b0.y; o[2] += b0.z; o[3] += b0.w;
            o[4] += b1.x; o[5] += b1.y; o[6] += b1.z; o[7] += b1.w;
        }
        float4* ob = (float4*)out + (size_t)node * 32 + fl * 2;
        ob[0] = make_float4(o[0], o[1], o[2], o[3]);
        ob[1] = make_float4(o[4], o[5], o[6], o[7]);
    }
}

// ---------- GEMM: out[RPB rows][NC] = A[RPB][K] @ W[K][NC] (+ bias) ----------
// A staged row-major [RPB][BK] in LDS; reads wave-broadcast, conflict-free.
// BF16OUT: write bf16 (packed) instead of fp32.
template<int K, int NC, int RPB, int MR, int BK, bool BF16OUT>
__global__ void k_gemm(const float* __restrict__ A, const float* __restrict__ W,
                       const float* __restrict__ bias, void* __restrict__ outp) {
    constexpr int NT = (NC / 4) * (RPB / MR);
    __shared__ float lds[RPB][BK];
    const int row0 = blockIdx.x * RPB;
    const int t = threadIdx.x;
    const int jc = (t % (NC / 4)) * 4;
    const int rc = (t / (NC / 4)) * MR;

    float4 acc[MR];
    #pragma unroll
    for (int m = 0; m < MR; ++m) acc[m] = make_float4(0.f, 0.f, 0.f, 0.f);

    for (int k0 = 0; k0 < K; k0 += BK) {
        if (k0 > 0) __syncthreads();
        constexpr int QUADS = RPB * BK / 4;
        #pragma unroll
        for (int i = 0; i < QUADS / NT; ++i) {
            int idx = i * NT + t;
            int r = idx / (BK / 4), k4 = idx % (BK / 4);
            int rg = row0 + r;
            if (rg >= N_NODES) rg = N_NODES - 1;  // tail clamp
            *(float4*)&lds[r][k4 * 4] = *(const float4*)&A[(size_t)rg * K + k0 + k4 * 4];
        }
        __syncthreads();

        #pragma unroll 2
        for (int kk = 0; kk < BK; kk += 4) {
            const float* wr = &W[(size_t)(k0 + kk) * NC + jc];
            float4 w0 = *(const float4*)(wr);
            float4 w1 = *(const float4*)(wr + NC);
            float4 w2 = *(const float4*)(wr + 2 * NC);
            float4 w3 = *(const float4*)(wr + 3 * NC);
            #pragma unroll
            for (int m = 0; m < MR; ++m) {
                float4 a = *(const float4*)&lds[rc + m][kk];  // broadcast
                acc[m].x = fmaf(a.x, w0.x, acc[m].x);
                acc[m].y = fmaf(a.x, w0.y, acc[m].y);
                acc[m].z = fmaf(a.x, w0.z, acc[m].z);
                acc[m].w = fmaf(a.x, w0.w, acc[m].w);
                acc[m].x = fmaf(a.y, w1.x, acc[m].x);
                acc[m].y = fmaf(a.y, w1.y, acc[m].y);
                acc[m].z = fmaf(a.y, w1.z, acc[m].z);
                acc[m].w = fmaf(a.y, w1.w, acc[m].w);
                acc[m].x = fmaf(a.z, w2.x, acc[m].x);
                acc[m].y = fmaf(a.z, w2.y, acc[m].y);
                acc[m].z = fmaf(a.z, w2.z, acc[m].z);
                acc[m].w = fmaf(a.z, w2.w, acc[m].w);
                acc[m].x = fmaf(a.w, w3.x, acc[m].x);
                acc[m].y = fmaf(a.w, w3.y, acc[m].y);
                acc[m].z = fmaf(a.w, w3.z, acc[m].z);
                acc[m].w = fmaf(a.w, w3.w, acc[m].w);
            }
        }
    }

    float4 b = make_float4(0.f, 0.f, 0.f, 0.f);
    if (bias) b = *(const float4*)&bias[jc];
    #pragma unroll
    for (int m = 0; m < MR; ++m) {
        int r = row0 + rc + m;
        if (r < N_NODES) {
            float4 o = acc[m];
            o.x += b.x; o.y += b.y; o.z += b.z; o.w += b.w;
            if constexpr (BF16OUT) {
                uint2 p;
                p.x = (uint)f2bf(o.x) | ((uint)f2bf(o.y) << 16);
                p.y = (uint)f2bf(o.z) | ((uint)f2bf(o.w) << 16);
                *(uint2*)((ushort*)outp + (size_t)r * NC + jc) = p;
            } else {
                *(float4*)((float*)outp + (size_t)r * NC + jc) = o;
            }
        }
    }
}

extern "C" void kernel_launch(void* const* d_in, const int* in_sizes, int n_in,
                              void* d_out, int out_size, void* d_ws, size_t ws_size,
                              hipStream_t stream) {
    const float* emb = (const float*)d_in[0];   // [50000][128]
    const float* W1  = (const float*)d_in[1];   // [128][256]
    const float* b1  = (const float*)d_in[2];   // [256]
    const float* W2  = (const float*)d_in[3];   // [256][128]
    const float* b2  = (const float*)d_in[4];   // [128]
    const int*   ei  = (const int*)d_in[5];     // [2][800000]
    const int* src = ei;
    const int* dst = ei + N_EDGES;

    char* ws = (char*)d_ws;
    float* dinv    = (float*)(ws);                    // 200 KB
    int*   counts  = (int*)  (ws + (256ull << 10));   // 200 KB
    int*   row_ptr = (int*)  (ws + (512ull << 10));   // 200 KB + 4
    int*   fill    = (int*)  (ws + (768ull << 10));   // 200 KB
    int*   bsum    = (int*)  (ws + (1008ull << 10));  // 784 B
    int*   boff    = (int*)  (ws + (1016ull << 10));  // 784 B
    int*   csr_src = (int*)  (ws + (1ull   << 20));   // 3.2 MB   (1..4.2 MB)
    uint*  emb_h   = (uint*) (ws + (5ull   << 20));   // 12.8 MB  (5..17.8 MB)
    uint*  x2_h    = (uint*) (ws + (18ull  << 20));   // 12.8 MB  (18..30.8 MB)
    float* agg0    = (float*)(ws + (18ull  << 20));   // 25.6 MB  (18..43.6) overlay: agg0 dead before x2_h written
    float* h       = (float*)(ws + (44ull  << 20));   // 51.2 MB  (44..95.2 MB)
    float* out     = (float*)d_out;

    // NOTE overlay: agg0 and x2_h share [18MB,30.8MB). Timeline: gather1 writes agg0,
    // GEMM1 reads agg0 -> h; GEMM2 reads h, writes x2_h (agg0 dead); gather2 reads x2_h.

    // bf16 shadow of emb (independent of CSR chain)
    k_tobf16<<<N_NODES * 128 / 8 / 256, 256, 0, stream>>>(emb, emb_h);

    // CSR build + normalization (device-wide 3-stage scan)
    k_zero<<<NB, 256, 0, stream>>>(counts);
    k_hist<<<(N_EDGES + 255) / 256, 256, 0, stream>>>(dst, counts);
    k_blocksum<<<NB, 256, 0, stream>>>(counts, bsum);
    k_scanb<<<1, 256, 0, stream>>>(bsum, boff);
    k_scatter_rp<<<NB, 256, 0, stream>>>(counts, boff, row_ptr, fill, dinv);
    k_fill<<<(N_EDGES + 255) / 256, 256, 0, stream>>>(src, dst, fill, csr_src);

    // layer 1 (reordered): agg0 = Agg(emb); h = agg0 @ W1 + b1
    k_gather128h<<<12500, 256, 0, stream>>>(emb_h, csr_src, row_ptr, dinv, nullptr, agg0);
    // K=128 NC=256 RPB=64 MR=8 BK=64 -> 512 threads, 16KB LDS
    k_gemm<128, 256, 64, 8, 64, false><<<(N_NODES + 63) / 64, 512, 0, stream>>>(agg0, W1, b1, h);

    // layer 2: x2_h = bf16(h @ W2) ; out = Agg(x2) + b2
    // K=256 NC=128 RPB=64 MR=8 BK=64 -> 256 threads, 16KB LDS
    k_gemm<256, 128, 64, 8, 64, true><<<(N_NODES + 63) / 64, 256, 0, stream>>>(h, W2, nullptr, (void*)x2_h);
    k_gather128h<<<12500, 256, 0, stream>>>(x2_h, csr_src, row_ptr, dinv, b2, out);
}